// Round 8
// baseline (314.629 us; speedup 1.0000x reference)
//
#include <hip/hip_runtime.h>
#include <hip/hip_bf16.h>

typedef __bf16 bf16x8 __attribute__((ext_vector_type(8)));
typedef __bf16 bf16x4 __attribute__((ext_vector_type(4)));
typedef float  f32x4  __attribute__((ext_vector_type(4)));

#define MFMA_BF16(a, b, c) __builtin_amdgcn_mfma_f32_16x16x32_bf16((a), (b), (c), 0, 0, 0)

typedef const __attribute__((address_space(1))) void* gas_ptr;
typedef __attribute__((address_space(3))) void* las_ptr;

__device__ __forceinline__ void gload_lds16(const void* g, void* l) {
    // async global->LDS, 16B per lane; LDS dest = uniform base + lane*16
    __builtin_amdgcn_global_load_lds((gas_ptr)g, (las_ptr)l, 16, 0, 0);
}

// raw v_exp_f32 (no OCML subnormal fixup; scores are well inside normal range)
__device__ __forceinline__ float fast_exp2(float x) {
#if __has_builtin(__builtin_amdgcn_exp2f)
    return __builtin_amdgcn_exp2f(x);
#else
    return __builtin_exp2f(x);
#endif
}

#define LOG2E 1.44269504088896f
#define QSCALE 0.1803368801111204f  // 0.125 * log2(e): folded into Q at GEMM1 epilogue

// ---------------------------------------------------------------------------
// prep: weight transposes only (x is no longer pre-converted — gemm1 reads
// f32 x directly). blocks [0,3072): qkv_w 1024x3072 -> bf16 [3072,1024];
// blocks [3072,4096): proj_w 1024x1024 -> bf16 [1024,1024].
__global__ __launch_bounds__(256) void prep_fused(const float* __restrict__ qkv_w,
                                                  const float* __restrict__ proj_w,
                                                  __bf16* __restrict__ Wqkvt,
                                                  __bf16* __restrict__ Wpt) {
    const int b = blockIdx.x;
    __shared__ float t[32][33];
    const float* in;
    __bf16* out;
    int R, C, bx, by;
    if (b < 3072) {
        in = qkv_w; out = Wqkvt; R = 1024; C = 3072;
        bx = (b % 96) * 32; by = (b / 96) * 32;
    } else {
        int bb = b - 3072;
        in = proj_w; out = Wpt; R = 1024; C = 1024;
        bx = (bb % 32) * 32; by = (bb / 32) * 32;
    }
    const int tx = threadIdx.x & 31, ty = threadIdx.x >> 5;
    int xcol = bx + tx;
    for (int j = ty; j < 32; j += 8)
        t[j][tx] = in[(size_t)(by + j) * C + xcol];
    __syncthreads();
    int x2 = by + tx;
    for (int j = ty; j < 32; j += 8)
        out[(size_t)(bx + j) * R + x2] = (__bf16)t[tx][j];
}

// ---------------------------------------------------------------------------
// GEMM1 (QKV): C = A_f32[M,K] * Bt_bf16[Nn,K]^T + bias, 128x128 tile, BK=32.
// A staged DIRECTLY as f32 (skips the 96MB x->bf16 pre-pass): 3-slot f32
// A-LDS (48KB) + bf16 B-LDS (24KB); in-register f32->bf16 cvt at fragment
// load (same RNE rounding as the old cvt kernel -> identical numerics).
// Counted vmcnt(6) rotation (6 loads/thread/tile: A=4, B=2), one s_barrier
// per K-step. XOR swizzles: A (8-slot, 128B rows) phys16B = s ^ (row&7);
// B (4-slot, 64B rows) phys16B = s ^ ((row>>1)&3); inverse on global source.
// Epilogue scatters Q (prescaled), K, V^T (sigma-permuted kpos).
__global__ __launch_bounds__(256) void gemm_f32a(const float* __restrict__ A,
                                                 const __bf16* __restrict__ Bt,
                                                 const float* __restrict__ bias,
                                                 __bf16* __restrict__ Qp,
                                                 __bf16* __restrict__ Kp,
                                                 __bf16* __restrict__ Vp,
                                                 int M, int Nn, int K) {
    __shared__ __align__(16) float  SA[3][4096];  // [slot][128 x 32 f32] swz8
    __shared__ __align__(16) __bf16 SB[3][4096];  // [slot][128 x 32 bf16] swz4
    const int tid = threadIdx.x, lane = tid & 63, w = tid >> 6;
    const int wr = w >> 1, wc = w & 1;
    const int nbx = Nn >> 7;
    const int nwg = (M >> 7) * nbx;
    const int cpx = nwg >> 3;
    const int id = blockIdx.x;
    const int nid = (id & 7) * cpx + (id >> 3);
    const int row0 = (nid / nbx) * 128, col0 = (nid % nbx) * 128;
    const float* Ag = A + (size_t)row0 * K;
    const __bf16* Bg = Bt + (size_t)col0 * K;
    // A staging: 16 chunks of 8 rows; lane covers row=(lane>>3), slot=lane&7
    const int arow = lane >> 3;
    const int srcA = ((lane & 7) ^ ((lane >> 3) & 7)) * 4;  // f32 elems
    // B staging: 8 chunks of 16 rows (old geometry)
    const int brow = lane >> 2;
    const int srcB = ((lane & 3) ^ ((lane >> 3) & 3)) * 8;  // bf16 elems
    const int frow = lane & 15, fq = lane >> 4;
    // fragment read offsets
    const int a0 = ((2 * fq) ^ (frow & 7)) * 4;      // f32 elems (16B slot)
    const int a1 = ((2 * fq + 1) ^ (frow & 7)) * 4;
    const int rdB = (fq ^ ((frow >> 1) & 3)) * 8;    // bf16 elems
    f32x4 acc[4][4];
    for (int i = 0; i < 4; ++i)
        for (int j = 0; j < 4; ++j) acc[i][j] = (f32x4)0.f;

    auto stage = [&](int t, float* Ad, __bf16* Bd) {
#pragma unroll
        for (int it = 0; it < 4; ++it) {
            int ci = 4 * w + it;  // 16 chunks of 8 rows
            gload_lds16(Ag + (size_t)(ci * 8 + arow) * K + t * 32 + srcA, Ad + ci * 256);
        }
#pragma unroll
        for (int it = 0; it < 2; ++it) {
            int ci = 2 * w + it;  // 8 chunks of 16 rows
            gload_lds16(Bg + (size_t)(ci * 16 + brow) * K + t * 32 + srcB, Bd + ci * 512);
        }
    };

    const int NK = K >> 5;
    float  *cA = SA[0], *nA = SA[1], *sA = SA[2];
    __bf16 *cB = SB[0], *nB = SB[1], *sB = SB[2];
    stage(0, cA, cB);
    stage(1, nA, nB);

    for (int t = 0; t < NK; ++t) {
        // gate: stage(t) landed; stage(t+1) (6 loads) stays in flight
        if (t < NK - 1)
            asm volatile("s_waitcnt vmcnt(6)" ::: "memory");
        else
            asm volatile("s_waitcnt vmcnt(0)" ::: "memory");
        __builtin_amdgcn_s_barrier();
        if (t + 2 < NK) stage(t + 2, sA, sB);

        bf16x8 af[4], bf[4];
#pragma unroll
        for (int i = 0; i < 4; ++i) {
            const float* rp = cA + (wr * 64 + i * 16 + frow) * 32;
            f32x4 lo = *(const f32x4*)(rp + a0);
            f32x4 hi = *(const f32x4*)(rp + a1);
            bf16x8 v;
            v[0] = (__bf16)lo[0]; v[1] = (__bf16)lo[1];
            v[2] = (__bf16)lo[2]; v[3] = (__bf16)lo[3];
            v[4] = (__bf16)hi[0]; v[5] = (__bf16)hi[1];
            v[6] = (__bf16)hi[2]; v[7] = (__bf16)hi[3];
            af[i] = v;
        }
#pragma unroll
        for (int j = 0; j < 4; ++j)
            bf[j] = *(const bf16x8*)&cB[(wc * 64 + j * 16 + frow) * 32 + rdB];
#pragma unroll
        for (int i = 0; i < 4; ++i)
#pragma unroll
            for (int j = 0; j < 4; ++j) acc[i][j] = MFMA_BF16(af[i], bf[j], acc[i][j]);

        float*  tA = cA; cA = nA; nA = sA; sA = tA;
        __bf16* tB = cB; cB = nB; nB = sB; sB = tB;
    }

    // epilogue: C/D layout col = lane&15, row = (lane>>4)*4 + reg
    for (int i = 0; i < 4; ++i) {
        int rbase = row0 + wr * 64 + i * 16 + fq * 4;
        for (int j = 0; j < 4; ++j) {
            int c = col0 + wc * 64 + j * 16 + frow;
            float bv = bias[c];
            int which = c >> 10;
            int h = (c >> 6) & 15;
            int d = c & 63;
            if (which == 2) {
                int b = rbase >> 11, n = rbase & 2047;
                int nph = (n & ~31) | (((n >> 2) & 3) << 3) | (((n >> 4) & 1) << 2) |
                          (n & 3);
                bf16x4 vv = {(__bf16)(acc[i][j][0] + bv), (__bf16)(acc[i][j][1] + bv),
                             (__bf16)(acc[i][j][2] + bv), (__bf16)(acc[i][j][3] + bv)};
                *(bf16x4*)&Vp[(size_t)(((b << 4) + h) * 64 + d) * 2048 + nph] = vv;
            } else {
                for (int rg = 0; rg < 4; ++rg) {
                    int rr = rbase + rg;
                    int b = rr >> 11, n = rr & 2047;
                    float v = acc[i][j][rg] + bv;
                    if (which == 0)
                        Qp[(size_t)(((b << 4) + h) * 2048 + n) * 64 + d] =
                            (__bf16)(v * QSCALE);
                    else
                        Kp[(size_t)(((b << 4) + h) * 2048 + n) * 64 + d] = (__bf16)v;
                }
            }
        }
    }
}

// ---------------------------------------------------------------------------
// GEMM2 (output projection): bf16 A/B, 128x128, BK=32, 3-slot counted vmcnt.
__global__ __launch_bounds__(256) void gemm_proj(const __bf16* __restrict__ A,
                                                 const __bf16* __restrict__ Bt,
                                                 const float* __restrict__ bias,
                                                 float* __restrict__ outp,
                                                 int M, int Nn, int K) {
    __shared__ __align__(16) __bf16 SA[3][4096];
    __shared__ __align__(16) __bf16 SB[3][4096];
    const int tid = threadIdx.x, lane = tid & 63, w = tid >> 6;
    const int wr = w >> 1, wc = w & 1;
    const int nbx = Nn >> 7;
    const int nwg = (M >> 7) * nbx;
    const int cpx = nwg >> 3;
    const int id = blockIdx.x;
    const int nid = (id & 7) * cpx + (id >> 3);
    const int row0 = (nid / nbx) * 128, col0 = (nid % nbx) * 128;
    const __bf16* Ag = A + (size_t)row0 * K;
    const __bf16* Bg = Bt + (size_t)col0 * K;
    const int lr = lane >> 2;
    const int srcc = ((lane & 3) ^ ((lane >> 3) & 3)) * 8;
    const int frow = lane & 15, fq = lane >> 4;
    const int rdoff = (fq ^ ((frow >> 1) & 3)) * 8;
    f32x4 acc[4][4];
    for (int i = 0; i < 4; ++i)
        for (int j = 0; j < 4; ++j) acc[i][j] = (f32x4)0.f;

    auto stage = [&](int t, __bf16* Ad, __bf16* Bd) {
#pragma unroll
        for (int it = 0; it < 2; ++it) {
            int ci = 2 * w + it;
            gload_lds16(Ag + (size_t)(ci * 16 + lr) * K + t * 32 + srcc, Ad + ci * 512);
            gload_lds16(Bg + (size_t)(ci * 16 + lr) * K + t * 32 + srcc, Bd + ci * 512);
        }
    };

    const int NK = K >> 5;
    __bf16 *cA = SA[0], *cB = SB[0];
    __bf16 *nA = SA[1], *nB = SB[1];
    __bf16 *sA = SA[2], *sB = SB[2];
    stage(0, cA, cB);
    stage(1, nA, nB);

    for (int t = 0; t < NK; ++t) {
        if (t < NK - 1)
            asm volatile("s_waitcnt vmcnt(4)" ::: "memory");
        else
            asm volatile("s_waitcnt vmcnt(0)" ::: "memory");
        __builtin_amdgcn_s_barrier();
        if (t + 2 < NK) stage(t + 2, sA, sB);

        bf16x8 af[4], bf[4];
#pragma unroll
        for (int i = 0; i < 4; ++i)
            af[i] = *(const bf16x8*)&cA[(wr * 64 + i * 16 + frow) * 32 + rdoff];
#pragma unroll
        for (int j = 0; j < 4; ++j)
            bf[j] = *(const bf16x8*)&cB[(wc * 64 + j * 16 + frow) * 32 + rdoff];
#pragma unroll
        for (int i = 0; i < 4; ++i)
#pragma unroll
            for (int j = 0; j < 4; ++j) acc[i][j] = MFMA_BF16(af[i], bf[j], acc[i][j]);

        __bf16* tA = cA; cA = nA; nA = sA; sA = tA;
        __bf16* tB = cB; cB = nB; nB = sB; sB = tB;
    }

    for (int i = 0; i < 4; ++i) {
        int rbase = row0 + wr * 64 + i * 16 + fq * 4;
        for (int j = 0; j < 4; ++j) {
            int c = col0 + wc * 64 + j * 16 + frow;
            float bv = bias[c];
            for (int rg = 0; rg < 4; ++rg)
                outp[(size_t)(rbase + rg) * Nn + c] = acc[i][j][rg] + bv;
        }
    }
}

// ---------------------------------------------------------------------------
// Flash attention v7 (unchanged -- at the plain-HIP attn plateau ~900 TF)
__global__ __launch_bounds__(256, 4) void flash_attn7(const __bf16* __restrict__ Q,
                                                      const __bf16* __restrict__ K,
                                                      const __bf16* __restrict__ Vt,
                                                      __bf16* __restrict__ O) {
    __shared__ __align__(16) __bf16 Kts[2][4096];  // [buf][d-half][kpos 64][32 d] (swz)
    __shared__ __align__(16) __bf16 Vts[2][4096];  // [buf][k-half][d 64][32 kphys] (swz)
    const int tid = threadIdx.x, lane = tid & 63, w = tid >> 6;
    const int frow = lane & 15, fq = lane >> 4;
    const int id = blockIdx.x;
    const int nid = (id & 7) * 128 + (id >> 3);
    const int bh = nid >> 4;
    const int q0 = (nid & 15) * 128;
    const __bf16* Qg = Q + ((size_t)bh * 2048 + q0 + w * 32) * 64;
    const __bf16* Kb = K + (size_t)bh * 2048 * 64;
    const __bf16* Vb = Vt + (size_t)bh * 64 * 2048;

    bf16x8 qf[2][2];
#pragma unroll
    for (int nt = 0; nt < 2; ++nt)
#pragma unroll
        for (int ks = 0; ks < 2; ++ks)
            qf[nt][ks] = *(const bf16x8*)(Qg + (nt * 16 + frow) * 64 + ks * 32 + fq * 8);

    bf16x8 ones;
#pragma unroll
    for (int i = 0; i < 8; ++i) ones[i] = (__bf16)1.0f;

    f32x4 acc[2][4];
#pragma unroll
    for (int i = 0; i < 2; ++i)
#pragma unroll
        for (int j = 0; j < 4; ++j) acc[i][j] = (f32x4)0.f;
    f32x4 acc_l[2];
#pragma unroll
    for (int i = 0; i < 2; ++i) acc_l[i] = (f32x4)0.f;

    const int s_r16 = lane >> 2;
    const int s_c8 = (((lane & 3) ^ ((lane >> 3) & 3))) * 8;

    auto stage = [&](int kt, __bf16* Kd, __bf16* Vd) {
#pragma unroll
        for (int it = 0; it < 2; ++it) {
            int ci = 2 * w + it;
            int ks = ci >> 2;
            int r16 = (ci & 3) * 16 + s_r16;
            gload_lds16(Kb + (size_t)(kt * 64 + r16) * 64 + ks * 32 + s_c8, Kd + ci * 512);
            gload_lds16(Vb + (size_t)r16 * 2048 + kt * 64 + ks * 32 + s_c8, Vd + ci * 512);
        }
    };

    stage(0, Kts[0], Vts[0]);

    const int key = (frow >> 1) & 3;
    const int slot = (fq ^ key) * 8;

    auto body = [&](int kt, const __bf16* Kc, const __bf16* Vc, __bf16* Kn, __bf16* Vn) {
        __syncthreads();
        if (kt < 31) stage(kt + 1, Kn, Vn);

#pragma unroll
        for (int ph = 0; ph < 2; ++ph) {
            bf16x8 pf[2];
#pragma unroll
            for (int mi = 0; mi < 2; ++mi) {
                int mt = ph * 2 + mi;
                bf16x8 a0 = *(const bf16x8*)&Kc[(mt * 16 + frow) * 32 + slot];
                bf16x8 a1 = *(const bf16x8*)&Kc[2048 + (mt * 16 + frow) * 32 + slot];
#pragma unroll
                for (int nt = 0; nt < 2; ++nt) {
                    f32x4 s = MFMA_BF16(a0, qf[nt][0], (f32x4)0.f);
                    s = MFMA_BF16(a1, qf[nt][1], s);
                    pf[nt][mi * 4 + 0] = (__bf16)fast_exp2(s[0]);
                    pf[nt][mi * 4 + 1] = (__bf16)fast_exp2(s[1]);
                    pf[nt][mi * 4 + 2] = (__bf16)fast_exp2(s[2]);
                    pf[nt][mi * 4 + 3] = (__bf16)fast_exp2(s[3]);
                }
            }

            __builtin_amdgcn_s_setprio(1);
#pragma unroll
            for (int nt = 0; nt < 4; ++nt) {
                bf16x8 vf = *(const bf16x8*)&Vc[ph * 2048 + (nt * 16 + frow) * 32 + slot];
                acc[0][nt] = MFMA_BF16(pf[0], vf, acc[0][nt]);
                acc[1][nt] = MFMA_BF16(pf[1], vf, acc[1][nt]);
            }
            acc_l[0] = MFMA_BF16(pf[0], ones, acc_l[0]);
            acc_l[1] = MFMA_BF16(pf[1], ones, acc_l[1]);
            __builtin_amdgcn_s_setprio(0);
        }
    };

    for (int kt = 0; kt < 32; kt += 2) {
        body(kt, Kts[0], Vts[0], Kts[1], Vts[1]);
        body(kt + 1, Kts[1], Vts[1], Kts[0], Vts[0]);
    }

    const int b = bh >> 4, h = bh & 15;
#pragma unroll
    for (int mq = 0; mq < 2; ++mq)
#pragma unroll
        for (int r = 0; r < 4; ++r) {
            float linv = 1.0f / acc_l[mq][r];
            int qg = q0 + w * 32 + mq * 16 + fq * 4 + r;
            __bf16* orow = O + ((size_t)(b * 2048 + qg)) * 1024 + h * 64 + frow;
#pragma unroll
            for (int nt = 0; nt < 4; ++nt)
                orow[nt * 16] = (__bf16)(acc[mq][nt][r] * linv);
        }
}

// ---------------------------------------------------------------------------
extern "C" void kernel_launch(void* const* d_in, const int* in_sizes, int n_in,
                              void* d_out, int out_size, void* d_ws, size_t ws_size,
                              hipStream_t stream) {
    const float* x      = (const float*)d_in[0];  // [4,2048,1024]
    const float* qkv_w  = (const float*)d_in[1];  // [1024,3072]
    const float* qkv_b  = (const float*)d_in[2];  // [3072]
    const float* proj_w = (const float*)d_in[3];  // [1024,1024]
    const float* proj_b = (const float*)d_in[4];  // [1024]
    float* out = (float*)d_out;                   // [4,2048,1024]

    char* ws = (char*)d_ws;
    __bf16* Wqkvt   = (__bf16*)(ws);              //  6,291,456 B
    __bf16* Wpt     = (__bf16*)(ws + 6291456);    //  2,097,152 B
    __bf16* Qb      = (__bf16*)(ws + 8388608);    // 16,777,216 B  (prescaled)
    __bf16* Kb      = (__bf16*)(ws + 25165824);   // 16,777,216 B
    __bf16* Vtb     = (__bf16*)(ws + 41943040);   // 16,777,216 B  ([b,h,d,n] sigma-perm)
    __bf16* AttnOut = (__bf16*)(ws + 58720256);   // 16,777,216 B

    prep_fused<<<4096, 256, 0, stream>>>(qkv_w, proj_w, Wqkvt, Wpt);

    gemm_f32a<<<1536, 256, 0, stream>>>(x, Wqkvt, qkv_b, Qb, Kb, Vtb, 8192, 3072, 1024);

    flash_attn7<<<1024, 256, 0, stream>>>(Qb, Kb, Vtb, AttnOut);

    gemm_proj<<<512, 256, 0, stream>>>(AttnOut, Wpt, proj_b, out, 8192, 1024, 1024);
}

// Round 9
// 261.143 us; speedup vs baseline: 1.2048x; 1.2048x over previous
//
#include <hip/hip_runtime.h>
#include <hip/hip_bf16.h>

typedef __bf16 bf16x8 __attribute__((ext_vector_type(8)));
typedef __bf16 bf16x4 __attribute__((ext_vector_type(4)));
typedef float  f32x4  __attribute__((ext_vector_type(4)));

#define MFMA_BF16(a, b, c) __builtin_amdgcn_mfma_f32_16x16x32_bf16((a), (b), (c), 0, 0, 0)

typedef const __attribute__((address_space(1))) void* gas_ptr;
typedef __attribute__((address_space(3))) void* las_ptr;

__device__ __forceinline__ void gload_lds16(const void* g, void* l) {
    // async global->LDS, 16B per lane; LDS dest = uniform base + lane*16
    __builtin_amdgcn_global_load_lds((gas_ptr)g, (las_ptr)l, 16, 0, 0);
}

// raw v_exp_f32 (no OCML subnormal fixup; scores are well inside normal range)
__device__ __forceinline__ float fast_exp2(float x) {
#if __has_builtin(__builtin_amdgcn_exp2f)
    return __builtin_amdgcn_exp2f(x);
#else
    return __builtin_exp2f(x);
#endif
}

#define LOG2E 1.44269504088896f
#define QSCALE 0.1803368801111204f  // 0.125 * log2(e): folded into Q at GEMM1 epilogue

// ---------------------------------------------------------------------------
// Fused prep: one launch (cvt x, transpose qkv_w, transpose proj_w).
// blocks [0,8192): f32->bf16 cvt of x; [8192,11264): qkv_w transpose;
// [11264,12288): proj_w transpose. Branch is block-uniform.
__global__ __launch_bounds__(256) void prep_fused(const float* __restrict__ x,
                                                  const float* __restrict__ qkv_w,
                                                  const float* __restrict__ proj_w,
                                                  __bf16* __restrict__ Xb,
                                                  __bf16* __restrict__ Wqkvt,
                                                  __bf16* __restrict__ Wpt) {
    const int b = blockIdx.x;
    if (b < 8192) {
        int i = b * 256 + threadIdx.x;
        float4 v = ((const float4*)x)[i];
        bf16x4 o = {(__bf16)v.x, (__bf16)v.y, (__bf16)v.z, (__bf16)v.w};
        ((bf16x4*)Xb)[i] = o;
        return;
    }
    __shared__ float t[32][33];
    const float* in;
    __bf16* out;
    int R, C, bx, by;
    if (b < 11264) {
        int bb = b - 8192;
        in = qkv_w; out = Wqkvt; R = 1024; C = 3072;
        bx = (bb % 96) * 32; by = (bb / 96) * 32;
    } else {
        int bb = b - 11264;
        in = proj_w; out = Wpt; R = 1024; C = 1024;
        bx = (bb % 32) * 32; by = (bb / 32) * 32;
    }
    const int tx = threadIdx.x & 31, ty = threadIdx.x >> 5;
    int xcol = bx + tx;
    for (int j = ty; j < 32; j += 8)
        t[j][tx] = in[(size_t)(by + j) * C + xcol];
    __syncthreads();
    int x2 = by + tx;
    for (int j = ty; j < 32; j += 8)
        out[(size_t)(bx + j) * R + x2] = (__bf16)t[tx][j];
}

// ---------------------------------------------------------------------------
// GEMM: C[M,Nn] = A[M,K] * Bt[Nn,K]^T + bias.  128x128 tile, BK=32.
// K-loop: 3-slot LDS rotation, ONE raw s_barrier per K-step, counted
// vmcnt(4) gate (never 0 in the loop) -> stage(t+1) stays in flight across
// the barrier; stage(t+2) issued each step = 2-K-step prefetch depth.
// XOR-swizzled LDS (phys 16B-slot = fq ^ ((row>>1)&3); inverse applied to
// the global source column at staging) -> conflict-free ds_read_b128.
// 1D grid with XCD-chunked swizzle (nwg % 8 == 0 for our shapes).
// MODE 0: scatter bf16 into Q (prescaled by QSCALE) [B,H,N,D], K [B,H,N,D],
//         and V TRANSPOSED [B,H,D,N] with within-32 kpos permutation sigma:
//         n_phys = (n&~31) | ((n>>2)&3)<<3 | ((n>>4)&1)<<2 | (n&3)
//         so flash's PV B-fragment (kpos = 16*(j>>2)+4*fq+(j&3)) is one b128.
// MODE 1: fp32 out[M,Nn]
template <int MODE>
__global__ __launch_bounds__(256) void gemm_bt(const __bf16* __restrict__ A,
                                               const __bf16* __restrict__ Bt,
                                               const float* __restrict__ bias,
                                               float* __restrict__ outp,
                                               __bf16* __restrict__ Qp,
                                               __bf16* __restrict__ Kp,
                                               __bf16* __restrict__ Vp,
                                               int M, int Nn, int K) {
    __shared__ __align__(16) __bf16 SA[3][4096];  // [slot][128 rows x 32 cols] (swz)
    __shared__ __align__(16) __bf16 SB[3][4096];
    const int tid = threadIdx.x, lane = tid & 63, w = tid >> 6;
    const int wr = w >> 1, wc = w & 1;
    const int nbx = Nn >> 7;
    const int nwg = (M >> 7) * nbx;
    const int cpx = nwg >> 3;
    const int id = blockIdx.x;
    const int nid = (id & 7) * cpx + (id >> 3);
    const int row0 = (nid / nbx) * 128, col0 = (nid % nbx) * 128;
    const __bf16* Ag = A + (size_t)row0 * K;
    const __bf16* Bg = Bt + (size_t)col0 * K;
    const int lr = lane >> 2;  // 0..15 row within 16-row chunk
    const int srcc = ((lane & 3) ^ ((lane >> 3) & 3)) * 8;
    const int frow = lane & 15, fq = lane >> 4;
    const int rdoff = (fq ^ ((frow >> 1) & 3)) * 8;
    f32x4 acc[4][4];
    for (int i = 0; i < 4; ++i)
        for (int j = 0; j < 4; ++j) acc[i][j] = (f32x4)0.f;

    auto stage = [&](int t, __bf16* Ad, __bf16* Bd) {
#pragma unroll
        for (int it = 0; it < 2; ++it) {
            int ci = 2 * w + it;  // 8 chunks of 16 rows
            gload_lds16(Ag + (size_t)(ci * 16 + lr) * K + t * 32 + srcc, Ad + ci * 512);
            gload_lds16(Bg + (size_t)(ci * 16 + lr) * K + t * 32 + srcc, Bd + ci * 512);
        }
    };

    const int NK = K >> 5;
    __bf16 *cA = SA[0], *cB = SB[0];
    __bf16 *nA = SA[1], *nB = SB[1];
    __bf16 *sA = SA[2], *sB = SB[2];
    stage(0, cA, cB);
    stage(1, nA, nB);

    for (int t = 0; t < NK; ++t) {
        // gate: stage(t) landed; stage(t+1) stays in flight (counted, never 0
        // except the final step where nothing newer is pending)
        if (t < NK - 1)
            asm volatile("s_waitcnt vmcnt(4)" ::: "memory");
        else
            asm volatile("s_waitcnt vmcnt(0)" ::: "memory");
        __builtin_amdgcn_s_barrier();  // publishes slot(t)
        if (t + 2 < NK) stage(t + 2, sA, sB);

        bf16x8 af[4], bf[4];
#pragma unroll
        for (int i = 0; i < 4; ++i)
            af[i] = *(const bf16x8*)&cA[(wr * 64 + i * 16 + frow) * 32 + rdoff];
#pragma unroll
        for (int j = 0; j < 4; ++j)
            bf[j] = *(const bf16x8*)&cB[(wc * 64 + j * 16 + frow) * 32 + rdoff];
#pragma unroll
        for (int i = 0; i < 4; ++i)
#pragma unroll
            for (int j = 0; j < 4; ++j) acc[i][j] = MFMA_BF16(af[i], bf[j], acc[i][j]);

        __bf16* tA = cA; cA = nA; nA = sA; sA = tA;
        __bf16* tB = cB; cB = nB; nB = sB; sB = tB;
    }

    // epilogue: C/D layout col = lane&15, row = (lane>>4)*4 + reg
    for (int i = 0; i < 4; ++i) {
        int rbase = row0 + wr * 64 + i * 16 + fq * 4;
        for (int j = 0; j < 4; ++j) {
            int c = col0 + wc * 64 + j * 16 + frow;
            float bv = bias[c];
            if (MODE == 0) {
                int which = c >> 10;
                int h = (c >> 6) & 15;
                int d = c & 63;
                if (which == 2) {
                    int b = rbase >> 11, n = rbase & 2047;
                    int nph = (n & ~31) | (((n >> 2) & 3) << 3) | (((n >> 4) & 1) << 2) |
                              (n & 3);
                    bf16x4 vv = {(__bf16)(acc[i][j][0] + bv), (__bf16)(acc[i][j][1] + bv),
                                 (__bf16)(acc[i][j][2] + bv), (__bf16)(acc[i][j][3] + bv)};
                    *(bf16x4*)&Vp[(size_t)(((b << 4) + h) * 64 + d) * 2048 + nph] = vv;
                } else {
                    for (int rg = 0; rg < 4; ++rg) {
                        int rr = rbase + rg;
                        int b = rr >> 11, n = rr & 2047;
                        float v = acc[i][j][rg] + bv;
                        if (which == 0)
                            Qp[(size_t)(((b << 4) + h) * 2048 + n) * 64 + d] =
                                (__bf16)(v * QSCALE);
                        else
                            Kp[(size_t)(((b << 4) + h) * 2048 + n) * 64 + d] = (__bf16)v;
                    }
                }
            } else {
                for (int rg = 0; rg < 4; ++rg)
                    outp[(size_t)(rbase + rg) * Nn + c] = acc[i][j][rg] + bv;
            }
        }
    }
}

// ---------------------------------------------------------------------------
// Flash attention v8: 1D grid 1024 (XCD-swizzled); block 256 = 4 waves,
// 32 q-rows/wave. S^T = K Q^T; no max tracking; Q prescaled.
// v8 vs v7: s_setprio(1) also around the QK^T MFMA pairs (was PV-only) —
// waves drift across QK/exp2/PV phases between barriers; prioritizing all
// matrix-pipe clusters lets exp2-busy waves yield issue slots (m191 attn
// +4-7%). Everything else identical to v7.
__global__ __launch_bounds__(256, 4) void flash_attn8(const __bf16* __restrict__ Q,
                                                      const __bf16* __restrict__ K,
                                                      const __bf16* __restrict__ Vt,
                                                      __bf16* __restrict__ O) {
    __shared__ __align__(16) __bf16 Kts[2][4096];  // [buf][d-half][kpos 64][32 d] (swz)
    __shared__ __align__(16) __bf16 Vts[2][4096];  // [buf][k-half][d 64][32 kphys] (swz)
    const int tid = threadIdx.x, lane = tid & 63, w = tid >> 6;
    const int frow = lane & 15, fq = lane >> 4;
    const int id = blockIdx.x;
    const int nid = (id & 7) * 128 + (id >> 3);
    const int bh = nid >> 4;
    const int q0 = (nid & 15) * 128;
    const __bf16* Qg = Q + ((size_t)bh * 2048 + q0 + w * 32) * 64;
    const __bf16* Kb = K + (size_t)bh * 2048 * 64;
    const __bf16* Vb = Vt + (size_t)bh * 64 * 2048;

    bf16x8 qf[2][2];
#pragma unroll
    for (int nt = 0; nt < 2; ++nt)
#pragma unroll
        for (int ks = 0; ks < 2; ++ks)
            qf[nt][ks] = *(const bf16x8*)(Qg + (nt * 16 + frow) * 64 + ks * 32 + fq * 8);

    bf16x8 ones;
#pragma unroll
    for (int i = 0; i < 8; ++i) ones[i] = (__bf16)1.0f;

    f32x4 acc[2][4];
#pragma unroll
    for (int i = 0; i < 2; ++i)
#pragma unroll
        for (int j = 0; j < 4; ++j) acc[i][j] = (f32x4)0.f;
    f32x4 acc_l[2];
#pragma unroll
    for (int i = 0; i < 2; ++i) acc_l[i] = (f32x4)0.f;

    const int s_r16 = lane >> 2;
    const int s_c8 = (((lane & 3) ^ ((lane >> 3) & 3))) * 8;

    auto stage = [&](int kt, __bf16* Kd, __bf16* Vd) {
#pragma unroll
        for (int it = 0; it < 2; ++it) {
            int ci = 2 * w + it;
            int ks = ci >> 2;
            int r16 = (ci & 3) * 16 + s_r16;
            gload_lds16(Kb + (size_t)(kt * 64 + r16) * 64 + ks * 32 + s_c8, Kd + ci * 512);
            gload_lds16(Vb + (size_t)r16 * 2048 + kt * 64 + ks * 32 + s_c8, Vd + ci * 512);
        }
    };

    stage(0, Kts[0], Vts[0]);

    const int key = (frow >> 1) & 3;
    const int slot = (fq ^ key) * 8;

    auto body = [&](int kt, const __bf16* Kc, const __bf16* Vc, __bf16* Kn, __bf16* Vn) {
        __syncthreads();
        if (kt < 31) stage(kt + 1, Kn, Vn);

#pragma unroll
        for (int ph = 0; ph < 2; ++ph) {
            bf16x8 pf[2];
#pragma unroll
            for (int mi = 0; mi < 2; ++mi) {
                int mt = ph * 2 + mi;
                bf16x8 a0 = *(const bf16x8*)&Kc[(mt * 16 + frow) * 32 + slot];
                bf16x8 a1 = *(const bf16x8*)&Kc[2048 + (mt * 16 + frow) * 32 + slot];
#pragma unroll
                for (int nt = 0; nt < 2; ++nt) {
                    __builtin_amdgcn_s_setprio(1);
                    f32x4 s = MFMA_BF16(a0, qf[nt][0], (f32x4)0.f);
                    s = MFMA_BF16(a1, qf[nt][1], s);
                    __builtin_amdgcn_s_setprio(0);
                    pf[nt][mi * 4 + 0] = (__bf16)fast_exp2(s[0]);
                    pf[nt][mi * 4 + 1] = (__bf16)fast_exp2(s[1]);
                    pf[nt][mi * 4 + 2] = (__bf16)fast_exp2(s[2]);
                    pf[nt][mi * 4 + 3] = (__bf16)fast_exp2(s[3]);
                }
            }

            __builtin_amdgcn_s_setprio(1);
#pragma unroll
            for (int nt = 0; nt < 4; ++nt) {
                bf16x8 vf = *(const bf16x8*)&Vc[ph * 2048 + (nt * 16 + frow) * 32 + slot];
                acc[0][nt] = MFMA_BF16(pf[0], vf, acc[0][nt]);
                acc[1][nt] = MFMA_BF16(pf[1], vf, acc[1][nt]);
            }
            acc_l[0] = MFMA_BF16(pf[0], ones, acc_l[0]);
            acc_l[1] = MFMA_BF16(pf[1], ones, acc_l[1]);
            __builtin_amdgcn_s_setprio(0);
        }
    };

    for (int kt = 0; kt < 32; kt += 2) {
        body(kt, Kts[0], Vts[0], Kts[1], Vts[1]);
        body(kt + 1, Kts[1], Vts[1], Kts[0], Vts[0]);
    }

    const int b = bh >> 4, h = bh & 15;
#pragma unroll
    for (int mq = 0; mq < 2; ++mq)
#pragma unroll
        for (int r = 0; r < 4; ++r) {
            float linv = 1.0f / acc_l[mq][r];
            int qg = q0 + w * 32 + mq * 16 + fq * 4 + r;
            __bf16* orow = O + ((size_t)(b * 2048 + qg)) * 1024 + h * 64 + frow;
#pragma unroll
            for (int nt = 0; nt < 4; ++nt)
                orow[nt * 16] = (__bf16)(acc[mq][nt][r] * linv);
        }
}

// ---------------------------------------------------------------------------
extern "C" void kernel_launch(void* const* d_in, const int* in_sizes, int n_in,
                              void* d_out, int out_size, void* d_ws, size_t ws_size,
                              hipStream_t stream) {
    const float* x      = (const float*)d_in[0];  // [4,2048,1024]
    const float* qkv_w  = (const float*)d_in[1];  // [1024,3072]
    const float* qkv_b  = (const float*)d_in[2];  // [3072]
    const float* proj_w = (const float*)d_in[3];  // [1024,1024]
    const float* proj_b = (const float*)d_in[4];  // [1024]
    float* out = (float*)d_out;                   // [4,2048,1024]

    char* ws = (char*)d_ws;
    // layout (72 MB total); AttnOut aliases Xb (dead after GEMM1)
    __bf16* Xb     = (__bf16*)(ws);               // 16,777,216 B
    __bf16* Wqkvt  = (__bf16*)(ws + 16777216);    //  6,291,456 B
    __bf16* Wpt    = (__bf16*)(ws + 23068672);    //  2,097,152 B
    __bf16* Qb     = (__bf16*)(ws + 25165824);    // 16,777,216 B  (prescaled)
    __bf16* Kb     = (__bf16*)(ws + 41943040);    // 16,777,216 B
    __bf16* Vtb    = (__bf16*)(ws + 58720256);    // 16,777,216 B  ([b,h,d,n] sigma-perm)
    __bf16* AttnOut = Xb;

    prep_fused<<<12288, 256, 0, stream>>>(x, qkv_w, proj_w, Xb, Wqkvt, Wpt);

    gemm_bt<0><<<1536, 256, 0, stream>>>(Xb, Wqkvt, qkv_b, nullptr,
                                         Qb, Kb, Vtb, 8192, 3072, 1024);

    flash_attn8<<<1024, 256, 0, stream>>>(Qb, Kb, Vtb, AttnOut);

    gemm_bt<1><<<512, 256, 0, stream>>>(AttnOut, Wpt, proj_b, out,
                                        nullptr, nullptr, nullptr, 8192, 1024, 1024);
}

// Round 11
// 257.182 us; speedup vs baseline: 1.2234x; 1.0154x over previous
//
#include <hip/hip_runtime.h>
#include <hip/hip_bf16.h>

typedef __bf16 bf16x8 __attribute__((ext_vector_type(8)));
typedef __bf16 bf16x4 __attribute__((ext_vector_type(4)));
typedef float  f32x4  __attribute__((ext_vector_type(4)));

#define MFMA_BF16(a, b, c) __builtin_amdgcn_mfma_f32_16x16x32_bf16((a), (b), (c), 0, 0, 0)

typedef const __attribute__((address_space(1))) void* gas_ptr;
typedef __attribute__((address_space(3))) void* las_ptr;

__device__ __forceinline__ void gload_lds16(const void* g, void* l) {
    // async global->LDS, 16B per lane; LDS dest = uniform base + lane*16
    __builtin_amdgcn_global_load_lds((gas_ptr)g, (las_ptr)l, 16, 0, 0);
}

// raw v_exp_f32 (no OCML subnormal fixup; scores are well inside normal range)
__device__ __forceinline__ float fast_exp2(float x) {
#if __has_builtin(__builtin_amdgcn_exp2f)
    return __builtin_amdgcn_exp2f(x);
#else
    return __builtin_exp2f(x);
#endif
}

#define LOG2E 1.44269504088896f
#define QSCALE 0.1803368801111204f  // 0.125 * log2(e): folded into Q at GEMM1 epilogue

// ---------------------------------------------------------------------------
// Fused prep: one launch (cvt x, transpose qkv_w, transpose proj_w).
__global__ __launch_bounds__(256) void prep_fused(const float* __restrict__ x,
                                                  const float* __restrict__ qkv_w,
                                                  const float* __restrict__ proj_w,
                                                  __bf16* __restrict__ Xb,
                                                  __bf16* __restrict__ Wqkvt,
                                                  __bf16* __restrict__ Wpt) {
    const int b = blockIdx.x;
    if (b < 8192) {
        int i = b * 256 + threadIdx.x;
        float4 v = ((const float4*)x)[i];
        bf16x4 o = {(__bf16)v.x, (__bf16)v.y, (__bf16)v.z, (__bf16)v.w};
        ((bf16x4*)Xb)[i] = o;
        return;
    }
    __shared__ float t[32][33];
    const float* in;
    __bf16* out;
    int R, C, bx, by;
    if (b < 11264) {
        int bb = b - 8192;
        in = qkv_w; out = Wqkvt; R = 1024; C = 3072;
        bx = (bb % 96) * 32; by = (bb / 96) * 32;
    } else {
        int bb = b - 11264;
        in = proj_w; out = Wpt; R = 1024; C = 1024;
        bx = (bb % 32) * 32; by = (bb / 32) * 32;
    }
    const int tx = threadIdx.x & 31, ty = threadIdx.x >> 5;
    int xcol = bx + tx;
    for (int j = ty; j < 32; j += 8)
        t[j][tx] = in[(size_t)(by + j) * C + xcol];
    __syncthreads();
    int x2 = by + tx;
    for (int j = ty; j < 32; j += 8)
        out[(size_t)(bx + j) * R + x2] = (__bf16)t[tx][j];
}

// ---------------------------------------------------------------------------
// GEMM: C[M,Nn] = A[M,K] * Bt[Nn,K]^T + bias.  128x128 tile, BK=32.
// v3 K-loop: 3-slot LDS rotation + TWO fragment register sets (software
// pipeline): after the barrier publishing slot t+1, issue the 8 ds_read_b128
// for frags(t+1) FIRST, then the 16 MFMA on frags(t) -> LDS pipe overlaps
// matrix pipe within the wave. Counted vmcnt(4) gate (never 0 mid-loop).
// WAR safety: raw s_barrier does NOT drain lgkm, so an explicit lgkmcnt(0)
// BEFORE each barrier guarantees the previous step's frag reads retired
// before any wave's stage() overwrites that slot (normally free: those reads
// had a full MFMA cluster to complete). Loop unrolled x2 so both register
// sets are statically named (no runtime indexing -> no scratch).
// XOR-swizzled LDS (conflict-free b128); XCD-chunked 1D grid swizzle.
// MODE 0: scatter Q (prescaled), K, V^T (sigma-permuted kpos).
// MODE 1: fp32 out[M,Nn].
template <int MODE>
__global__ __launch_bounds__(256, 3) void gemm_bt(const __bf16* __restrict__ A,
                                                  const __bf16* __restrict__ Bt,
                                                  const float* __restrict__ bias,
                                                  float* __restrict__ outp,
                                                  __bf16* __restrict__ Qp,
                                                  __bf16* __restrict__ Kp,
                                                  __bf16* __restrict__ Vp,
                                                  int M, int Nn, int K) {
    __shared__ __align__(16) __bf16 SA[3][4096];  // [slot][128 rows x 32 cols] (swz)
    __shared__ __align__(16) __bf16 SB[3][4096];
    const int tid = threadIdx.x, lane = tid & 63, w = tid >> 6;
    const int wr = w >> 1, wc = w & 1;
    const int nbx = Nn >> 7;
    const int nwg = (M >> 7) * nbx;
    const int cpx = nwg >> 3;
    const int id = blockIdx.x;
    const int nid = (id & 7) * cpx + (id >> 3);
    const int row0 = (nid / nbx) * 128, col0 = (nid % nbx) * 128;
    const __bf16* Ag = A + (size_t)row0 * K;
    const __bf16* Bg = Bt + (size_t)col0 * K;
    const int lr = lane >> 2;  // 0..15 row within 16-row chunk
    const int srcc = ((lane & 3) ^ ((lane >> 3) & 3)) * 8;
    const int frow = lane & 15, fq = lane >> 4;
    const int rdoff = (fq ^ ((frow >> 1) & 3)) * 8;
    f32x4 acc[4][4];
    for (int i = 0; i < 4; ++i)
        for (int j = 0; j < 4; ++j) acc[i][j] = (f32x4)0.f;
    bf16x8 afA[4], bfA[4], afB[4], bfB[4];  // two frag sets (static names)

    auto stage = [&](int t, __bf16* Ad, __bf16* Bd) {
#pragma unroll
        for (int it = 0; it < 2; ++it) {
            int ci = 2 * w + it;  // 8 chunks of 16 rows
            gload_lds16(Ag + (size_t)(ci * 16 + lr) * K + t * 32 + srcc, Ad + ci * 512);
            gload_lds16(Bg + (size_t)(ci * 16 + lr) * K + t * 32 + srcc, Bd + ci * 512);
        }
    };
    auto readfr = [&](bf16x8* af, bf16x8* bf, const __bf16* cA, const __bf16* cB) {
#pragma unroll
        for (int i = 0; i < 4; ++i)
            af[i] = *(const bf16x8*)&cA[(wr * 64 + i * 16 + frow) * 32 + rdoff];
#pragma unroll
        for (int j = 0; j < 4; ++j)
            bf[j] = *(const bf16x8*)&cB[(wc * 64 + j * 16 + frow) * 32 + rdoff];
    };
    auto mfma16 = [&](const bf16x8* af, const bf16x8* bf) {
        __builtin_amdgcn_s_setprio(1);
#pragma unroll
        for (int i = 0; i < 4; ++i)
#pragma unroll
            for (int j = 0; j < 4; ++j) acc[i][j] = MFMA_BF16(af[i], bf[j], acc[i][j]);
        __builtin_amdgcn_s_setprio(0);
    };

    const int NK = K >> 5;  // even for all our shapes
    __bf16 *a0 = SA[0], *a1 = SA[1], *a2 = SA[2];
    __bf16 *b0 = SB[0], *b1 = SB[1], *b2 = SB[2];
    // prologue: slot0 = k0, slot1 = k1; gate k0; preload frags(0)
    stage(0, a0, b0);
    stage(1, a1, b1);
    asm volatile("s_waitcnt vmcnt(4)" ::: "memory");
    __builtin_amdgcn_s_barrier();
    readfr(afA, bfA, a0, b0);

    for (int t = 0; t < NK; t += 2) {
        // even half: compute frags(t) [set A], prefetch frags(t+1) [set B]
        if (t + 2 < NK) stage(t + 2, a2, b2);
        if (t + 2 < NK)
            asm volatile("s_waitcnt vmcnt(4)" ::: "memory");  // stage(t+1) landed
        else
            asm volatile("s_waitcnt vmcnt(0)" ::: "memory");
        asm volatile("s_waitcnt lgkmcnt(0)" ::: "memory");  // WAR: prev frag reads done
        __builtin_amdgcn_s_barrier();
        readfr(afB, bfB, a1, b1);  // t+1 < NK always here (NK even, t < NK)
        mfma16(afA, bfA);
        __bf16* tp;
        tp = a0; a0 = a1; a1 = a2; a2 = tp;
        tp = b0; b0 = b1; b1 = b2; b2 = tp;

        // odd half: compute frags(t+1) [set B], prefetch frags(t+2) [set A]
        if (t + 3 < NK) stage(t + 3, a2, b2);
        if (t + 3 < NK)
            asm volatile("s_waitcnt vmcnt(4)" ::: "memory");  // stage(t+2) landed
        else if (t + 2 < NK)
            asm volatile("s_waitcnt vmcnt(0)" ::: "memory");
        asm volatile("s_waitcnt lgkmcnt(0)" ::: "memory");
        __builtin_amdgcn_s_barrier();
        if (t + 2 < NK) readfr(afA, bfA, a1, b1);
        mfma16(afB, bfB);
        tp = a0; a0 = a1; a1 = a2; a2 = tp;
        tp = b0; b0 = b1; b1 = b2; b2 = tp;
    }

    // epilogue: C/D layout col = lane&15, row = (lane>>4)*4 + reg
    for (int i = 0; i < 4; ++i) {
        int rbase = row0 + wr * 64 + i * 16 + fq * 4;
        for (int j = 0; j < 4; ++j) {
            int c = col0 + wc * 64 + j * 16 + frow;
            float bv = bias[c];
            if (MODE == 0) {
                int which = c >> 10;
                int h = (c >> 6) & 15;
                int d = c & 63;
                if (which == 2) {
                    int b = rbase >> 11, n = rbase & 2047;
                    int nph = (n & ~31) | (((n >> 2) & 3) << 3) | (((n >> 4) & 1) << 2) |
                              (n & 3);
                    bf16x4 vv = {(__bf16)(acc[i][j][0] + bv), (__bf16)(acc[i][j][1] + bv),
                                 (__bf16)(acc[i][j][2] + bv), (__bf16)(acc[i][j][3] + bv)};
                    *(bf16x4*)&Vp[(size_t)(((b << 4) + h) * 64 + d) * 2048 + nph] = vv;
                } else {
                    for (int rg = 0; rg < 4; ++rg) {
                        int rr = rbase + rg;
                        int b = rr >> 11, n = rr & 2047;
                        float v = acc[i][j][rg] + bv;
                        if (which == 0)
                            Qp[(size_t)(((b << 4) + h) * 2048 + n) * 64 + d] =
                                (__bf16)(v * QSCALE);
                        else
                            Kp[(size_t)(((b << 4) + h) * 2048 + n) * 64 + d] = (__bf16)v;
                    }
                }
            } else {
                for (int rg = 0; rg < 4; ++rg)
                    outp[(size_t)(rbase + rg) * Nn + c] = acc[i][j][rg] + bv;
            }
        }
    }
}

// ---------------------------------------------------------------------------
// Flash attention v8 (setprio around QK and PV MFMA clusters; null vs v7 but
// harmless). At the plain-HIP attn plateau ~900 TF.
__global__ __launch_bounds__(256, 4) void flash_attn8(const __bf16* __restrict__ Q,
                                                      const __bf16* __restrict__ K,
                                                      const __bf16* __restrict__ Vt,
                                                      __bf16* __restrict__ O) {
    __shared__ __align__(16) __bf16 Kts[2][4096];  // [buf][d-half][kpos 64][32 d] (swz)
    __shared__ __align__(16) __bf16 Vts[2][4096];  // [buf][k-half][d 64][32 kphys] (swz)
    const int tid = threadIdx.x, lane = tid & 63, w = tid >> 6;
    const int frow = lane & 15, fq = lane >> 4;
    const int id = blockIdx.x;
    const int nid = (id & 7) * 128 + (id >> 3);
    const int bh = nid >> 4;
    const int q0 = (nid & 15) * 128;
    const __bf16* Qg = Q + ((size_t)bh * 2048 + q0 + w * 32) * 64;
    const __bf16* Kb = K + (size_t)bh * 2048 * 64;
    const __bf16* Vb = Vt + (size_t)bh * 64 * 2048;

    bf16x8 qf[2][2];
#pragma unroll
    for (int nt = 0; nt < 2; ++nt)
#pragma unroll
        for (int ks = 0; ks < 2; ++ks)
            qf[nt][ks] = *(const bf16x8*)(Qg + (nt * 16 + frow) * 64 + ks * 32 + fq * 8);

    bf16x8 ones;
#pragma unroll
    for (int i = 0; i < 8; ++i) ones[i] = (__bf16)1.0f;

    f32x4 acc[2][4];
#pragma unroll
    for (int i = 0; i < 2; ++i)
#pragma unroll
        for (int j = 0; j < 4; ++j) acc[i][j] = (f32x4)0.f;
    f32x4 acc_l[2];
#pragma unroll
    for (int i = 0; i < 2; ++i) acc_l[i] = (f32x4)0.f;

    const int s_r16 = lane >> 2;
    const int s_c8 = (((lane & 3) ^ ((lane >> 3) & 3))) * 8;

    auto stage = [&](int kt, __bf16* Kd, __bf16* Vd) {
#pragma unroll
        for (int it = 0; it < 2; ++it) {
            int ci = 2 * w + it;
            int ks = ci >> 2;
            int r16 = (ci & 3) * 16 + s_r16;
            gload_lds16(Kb + (size_t)(kt * 64 + r16) * 64 + ks * 32 + s_c8, Kd + ci * 512);
            gload_lds16(Vb + (size_t)r16 * 2048 + kt * 64 + ks * 32 + s_c8, Vd + ci * 512);
        }
    };

    stage(0, Kts[0], Vts[0]);

    const int key = (frow >> 1) & 3;
    const int slot = (fq ^ key) * 8;

    auto body = [&](int kt, const __bf16* Kc, const __bf16* Vc, __bf16* Kn, __bf16* Vn) {
        __syncthreads();
        if (kt < 31) stage(kt + 1, Kn, Vn);

#pragma unroll
        for (int ph = 0; ph < 2; ++ph) {
            bf16x8 pf[2];
#pragma unroll
            for (int mi = 0; mi < 2; ++mi) {
                int mt = ph * 2 + mi;
                bf16x8 a0 = *(const bf16x8*)&Kc[(mt * 16 + frow) * 32 + slot];
                bf16x8 a1 = *(const bf16x8*)&Kc[2048 + (mt * 16 + frow) * 32 + slot];
#pragma unroll
                for (int nt = 0; nt < 2; ++nt) {
                    __builtin_amdgcn_s_setprio(1);
                    f32x4 s = MFMA_BF16(a0, qf[nt][0], (f32x4)0.f);
                    s = MFMA_BF16(a1, qf[nt][1], s);
                    __builtin_amdgcn_s_setprio(0);
                    pf[nt][mi * 4 + 0] = (__bf16)fast_exp2(s[0]);
                    pf[nt][mi * 4 + 1] = (__bf16)fast_exp2(s[1]);
                    pf[nt][mi * 4 + 2] = (__bf16)fast_exp2(s[2]);
                    pf[nt][mi * 4 + 3] = (__bf16)fast_exp2(s[3]);
                }
            }

            __builtin_amdgcn_s_setprio(1);
#pragma unroll
            for (int nt = 0; nt < 4; ++nt) {
                bf16x8 vf = *(const bf16x8*)&Vc[ph * 2048 + (nt * 16 + frow) * 32 + slot];
                acc[0][nt] = MFMA_BF16(pf[0], vf, acc[0][nt]);
                acc[1][nt] = MFMA_BF16(pf[1], vf, acc[1][nt]);
            }
            acc_l[0] = MFMA_BF16(pf[0], ones, acc_l[0]);
            acc_l[1] = MFMA_BF16(pf[1], ones, acc_l[1]);
            __builtin_amdgcn_s_setprio(0);
        }
    };

    for (int kt = 0; kt < 32; kt += 2) {
        body(kt, Kts[0], Vts[0], Kts[1], Vts[1]);
        body(kt + 1, Kts[1], Vts[1], Kts[0], Vts[0]);
    }

    const int b = bh >> 4, h = bh & 15;
#pragma unroll
    for (int mq = 0; mq < 2; ++mq)
#pragma unroll
        for (int r = 0; r < 4; ++r) {
            float linv = 1.0f / acc_l[mq][r];
            int qg = q0 + w * 32 + mq * 16 + fq * 4 + r;
            __bf16* orow = O + ((size_t)(b * 2048 + qg)) * 1024 + h * 64 + frow;
#pragma unroll
            for (int nt = 0; nt < 4; ++nt)
                orow[nt * 16] = (__bf16)(acc[mq][nt][r] * linv);
        }
}

// ---------------------------------------------------------------------------
extern "C" void kernel_launch(void* const* d_in, const int* in_sizes, int n_in,
                              void* d_out, int out_size, void* d_ws, size_t ws_size,
                              hipStream_t stream) {
    const float* x      = (const float*)d_in[0];  // [4,2048,1024]
    const float* qkv_w  = (const float*)d_in[1];  // [1024,3072]
    const float* qkv_b  = (const float*)d_in[2];  // [3072]
    const float* proj_w = (const float*)d_in[3];  // [1024,1024]
    const float* proj_b = (const float*)d_in[4];  // [1024]
    float* out = (float*)d_out;                   // [4,2048,1024]

    char* ws = (char*)d_ws;
    // layout (72 MB total); AttnOut aliases Xb (dead after GEMM1)
    __bf16* Xb     = (__bf16*)(ws);               // 16,777,216 B
    __bf16* Wqkvt  = (__bf16*)(ws + 16777216);    //  6,291,456 B
    __bf16* Wpt    = (__bf16*)(ws + 23068672);    //  2,097,152 B
    __bf16* Qb     = (__bf16*)(ws + 25165824);    // 16,777,216 B  (prescaled)
    __bf16* Kb     = (__bf16*)(ws + 41943040);    // 16,777,216 B
    __bf16* Vtb    = (__bf16*)(ws + 58720256);    // 16,777,216 B  ([b,h,d,n] sigma-perm)
    __bf16* AttnOut = Xb;

    prep_fused<<<12288, 256, 0, stream>>>(x, qkv_w, proj_w, Xb, Wqkvt, Wpt);

    gemm_bt<0><<<1536, 256, 0, stream>>>(Xb, Wqkvt, qkv_b, nullptr,
                                         Qb, Kb, Vtb, 8192, 3072, 1024);

    flash_attn8<<<1024, 256, 0, stream>>>(Qb, Kb, Vtb, AttnOut);

    gemm_bt<1><<<512, 256, 0, stream>>>(AttnOut, Wpt, proj_b, out,
                                        nullptr, nullptr, nullptr, 8192, 1024, 1024);
}